// Round 1
// baseline (1010.188 us; speedup 1.0000x reference)
//
#include <hip/hip_runtime.h>
#include <math.h>

#define HH 512
#define WW 512
#define IMG (HH*WW)
#define NIMG_PER 96   // B*C = 32*3
#define NIMG 192      // pred + targ
#define NBIN 256      // max_r
#define EPSV 1e-8f

__device__ __forceinline__ int rev9(int i) {
    return (int)(__brev((unsigned)i) >> 23);
}

// ---------------------------------------------------------------------------
// Pass A: one block per (image-row). 512-pt complex DIF FFT of a real row.
// Output written in natural storage order; contents are bit-reversed in kx.
// ---------------------------------------------------------------------------
__global__ __launch_bounds__(256) void rowfft_kernel(
    const float* __restrict__ pred, const float* __restrict__ targ,
    float2* __restrict__ out, int img_base)
{
    __shared__ float sre[512], sim[512];
    __shared__ float twr[256], twi[256];
    const int t = threadIdx.x;

    // twiddle table: w_512^k = exp(-2*pi*i*k/512), k = 0..255
    {
        float s_, c_;
        sincosf(-6.283185307179586f * (float)t / 512.0f, &s_, &c_);
        twr[t] = c_; twi[t] = s_;
    }

    const int row = blockIdx.x;
    const int li  = blockIdx.y;
    const int g   = img_base + li;
    const float* src = (g < NIMG_PER ? pred + (size_t)g * IMG
                                     : targ + (size_t)(g - NIMG_PER) * IMG)
                       + (size_t)row * WW;

    sre[t]       = src[t];       sim[t]       = 0.0f;
    sre[t + 256] = src[t + 256]; sim[t + 256] = 0.0f;
    __syncthreads();

    #pragma unroll
    for (int s = 9; s >= 1; --s) {
        const int half = 1 << (s - 1);
        const int j    = t & (half - 1);
        const int i1   = ((t >> (s - 1)) << s) + j;
        const int i2   = i1 + half;
        const int tw   = j << (9 - s);
        const float ur = sre[i1], ui = sim[i1];
        const float vr = sre[i2], vi = sim[i2];
        const float dr = ur - vr, di = ui - vi;
        const float wr = twr[tw], wi = twi[tw];
        sre[i1] = ur + vr;            sim[i1] = ui + vi;
        sre[i2] = dr * wr - di * wi;  sim[i2] = dr * wi + di * wr;
        __syncthreads();
    }

    float2* dst = out + (size_t)li * IMG + (size_t)row * WW;
    dst[t]       = make_float2(sre[t],       sim[t]);
    dst[t + 256] = make_float2(sre[t + 256], sim[t + 256]);
}

// ---------------------------------------------------------------------------
// Pass B: one block per (image, 8-column tile). 8x 512-pt DIF FFT down the
// columns, then log(|F|^2 + eps) and radial-bin accumulation.
// True frequencies: ky = rev9(storage_row), kx = rev9(storage_col).
// ---------------------------------------------------------------------------
#define LCOLS 8
#define LSTR  520   // padded column stride (floats) -> conflict-free-ish

__global__ __launch_bounds__(256) void colfft_kernel(
    const float2* __restrict__ in, float* __restrict__ bins, int img_base)
{
    __shared__ float sre[LCOLS * LSTR], sim[LCOLS * LSTR];
    __shared__ float twr[256], twi[256];
    __shared__ float bsum[NBIN];
    const int t = threadIdx.x;

    {
        float s_, c_;
        sincosf(-6.283185307179586f * (float)t / 512.0f, &s_, &c_);
        twr[t] = c_; twi[t] = s_;
    }
    bsum[t] = 0.0f;

    const int li = blockIdx.y;
    const int x0 = blockIdx.x * LCOLS;
    const float2* src = in + (size_t)li * IMG;

    // load 8 columns: 64B-contiguous per row -> every fetched byte used
    #pragma unroll
    for (int it = 0; it < 16; ++it) {
        const int id = it * 256 + t;      // 0..4095
        const int y  = id >> 3;
        const int cl = id & 7;
        const float2 v = src[(size_t)y * WW + (x0 + cl)];
        sre[cl * LSTR + y] = v.x;
        sim[cl * LSTR + y] = v.y;
    }
    __syncthreads();

    #pragma unroll
    for (int s = 9; s >= 1; --s) {
        const int half = 1 << (s - 1);
        const int j    = t & (half - 1);
        const int i1   = ((t >> (s - 1)) << s) + j;
        const int i2   = i1 + half;
        const int tw   = j << (9 - s);
        const float wr = twr[tw], wi = twi[tw];
        #pragma unroll
        for (int c = 0; c < LCOLS; ++c) {
            float* re = sre + c * LSTR;
            float* im = sim + c * LSTR;
            const float ur = re[i1], ui = im[i1];
            const float vr = re[i2], vi = im[i2];
            const float dr = ur - vr, di = ui - vi;
            re[i1] = ur + vr;            im[i1] = ui + vi;
            re[i2] = dr * wr - di * wi;  im[i2] = dr * wi + di * wr;
        }
        __syncthreads();
    }

    // PSD -> log -> radial bins (LDS accumulate, then 1 global atomic/bin)
    #pragma unroll
    for (int it = 0; it < 16; ++it) {
        const int id = it * 256 + t;
        const int q  = id >> 3;           // storage row
        const int cl = id & 7;
        const float re = sre[cl * LSTR + q];
        const float im = sim[cl * LSTR + q];
        const float val = logf(re * re + im * im + EPSV);
        const int ky = rev9(q);
        const int kx = rev9(x0 + cl);
        const int dy = ky - 256, dx = kx - 256;
        const int r2 = dy * dy + dx * dx;
        const int b  = (int)sqrtf((float)r2);
        if (b < NBIN) atomicAdd(&bsum[b], val);
    }
    __syncthreads();

    const int g = img_base + li;
    atomicAdd(&bins[(size_t)g * NBIN + t], bsum[t]);
}

// ---------------------------------------------------------------------------
// Finalize: counts per bin (analytic), then mean(|sum_p - sum_t| / cnt).
// ---------------------------------------------------------------------------
__global__ __launch_bounds__(256) void finalize_kernel(
    const float* __restrict__ bins, float* __restrict__ out)
{
    __shared__ float cnt[NBIN];
    __shared__ float red[256];
    const int t = threadIdx.x;
    cnt[t] = 0.0f;
    __syncthreads();

    for (int id = t; id < IMG; id += 256) {
        const int y = id >> 9, x = id & 511;
        const int dy = y - 256, dx = x - 256;
        const int r2 = dy * dy + dx * dx;
        const int b  = (int)sqrtf((float)r2);
        if (b < NBIN) atomicAdd(&cnt[b], 1.0f);
    }
    __syncthreads();

    float acc = 0.0f;
    for (int id = t; id < NIMG_PER * NBIN; id += 256) {
        const int i = id >> 8;      // image pair index 0..95
        const int r = id & 255;     // bin
        const float d = fabsf(bins[(size_t)i * NBIN + r]
                            - bins[(size_t)(NIMG_PER + i) * NBIN + r]);
        acc += d / cnt[r];
    }
    red[t] = acc;
    __syncthreads();
    for (int w = 128; w > 0; w >>= 1) {
        if (t < w) red[t] += red[t + w];
        __syncthreads();
    }
    if (t == 0) out[0] = red[0] / (float)(NIMG_PER * NBIN);
}

// ---------------------------------------------------------------------------
extern "C" void kernel_launch(void* const* d_in, const int* in_sizes, int n_in,
                              void* d_out, int out_size, void* d_ws, size_t ws_size,
                              hipStream_t stream)
{
    const float* pred = (const float*)d_in[0];
    const float* targ = (const float*)d_in[1];
    float* out = (float*)d_out;

    char* ws = (char*)d_ws;
    float* bins = (float*)ws;                       // NIMG*NBIN f32 accumulators
    const size_t bins_bytes = (size_t)NIMG * NBIN * sizeof(float);
    const size_t off = (bins_bytes + 255) & ~(size_t)255;
    float2* cbuf = (float2*)(ws + off);

    const size_t per_img = (size_t)IMG * sizeof(float2);   // 2 MiB
    size_t avail = (ws_size > off) ? (ws_size - off) : 0;
    int chunk = (int)(avail / per_img);
    if (chunk > NIMG) chunk = NIMG;
    if (chunk < 1) chunk = 1;   // assumes ws_size >= ~2.2 MiB

    hipMemsetAsync(bins, 0, bins_bytes, stream);

    for (int base = 0; base < NIMG; base += chunk) {
        const int n = (NIMG - base < chunk) ? (NIMG - base) : chunk;
        dim3 gA(HH, n), gB(WW / LCOLS, n), blk(256);
        rowfft_kernel<<<gA, blk, 0, stream>>>(pred, targ, cbuf, base);
        colfft_kernel<<<gB, blk, 0, stream>>>(cbuf, bins, base);
    }

    finalize_kernel<<<dim3(1), dim3(256), 0, stream>>>(bins, out);
}

// Round 2
// 435.179 us; speedup vs baseline: 2.3213x; 2.3213x over previous
//
#include <hip/hip_runtime.h>
#include <math.h>

#define HH 512
#define WW 512
#define IMG (HH*WW)
#define NIMG_PER 96   // B*C = 32*3
#define NIMG 192      // pred + targ
#define NBIN 256      // max_r
#define EPSV 1e-8f

#define CSTR 264               // padded column count (257 used + 7 pad)
#define IMGC (512*CSTR)        // float2 elements per image in cbuf
#define NTILE 33               // ceil(257/8) column tiles

__device__ __forceinline__ int rev9(int i) {
    return (int)(__brev((unsigned)i) >> 23);
}

// ---------------------------------------------------------------------------
// Pass A: one block per (image row-PAIR). Pack rows (2y, 2y+1) as a+ib,
// one 512-pt complex DIF FFT, unpack Hermitian halves, write kx = 0..256.
// ---------------------------------------------------------------------------
__global__ __launch_bounds__(256) void rowfft_kernel(
    const float* __restrict__ pred, const float* __restrict__ targ,
    float2* __restrict__ out, int img_base)
{
    __shared__ float sre[512], sim[512];
    __shared__ float twr[256], twi[256];
    const int t = threadIdx.x;

    {
        float s_, c_;
        sincosf(-6.283185307179586f * (float)t / 512.0f, &s_, &c_);
        twr[t] = c_; twi[t] = s_;
    }

    const int pair = blockIdx.x;          // 0..255
    const int li   = blockIdx.y;
    const int g    = img_base + li;
    const float* src = (g < NIMG_PER ? pred + (size_t)g * IMG
                                     : targ + (size_t)(g - NIMG_PER) * IMG)
                       + (size_t)(2 * pair) * WW;

    sre[t]       = src[t];            sim[t]       = src[WW + t];
    sre[t + 256] = src[t + 256];      sim[t + 256] = src[WW + t + 256];
    __syncthreads();

    #pragma unroll
    for (int s = 9; s >= 1; --s) {
        const int half = 1 << (s - 1);
        const int j    = t & (half - 1);
        const int i1   = ((t >> (s - 1)) << s) + j;
        const int i2   = i1 + half;
        const int tw   = j << (9 - s);
        const float ur = sre[i1], ui = sim[i1];
        const float vr = sre[i2], vi = sim[i2];
        const float dr = ur - vr, di = ui - vi;
        const float wr = twr[tw], wi = twi[tw];
        sre[i1] = ur + vr;            sim[i1] = ui + vi;
        sre[i2] = dr * wr - di * wi;  sim[i2] = dr * wi + di * wr;
        __syncthreads();
    }

    // unpack: Z(k) is at storage rev9(k). F_a(k)=(P+conjQ)/2, F_b(k)=(P-conjQ)/(2i)
    float2* dstA = out + (size_t)li * IMGC + (size_t)(2 * pair) * CSTR;
    float2* dstB = dstA + CSTR;
    for (int k = t; k <= 256; k += 256) {        // t=0 also handles k=256
        const int p1 = rev9(k);
        const int p2 = rev9((512 - k) & 511);
        const float Pr = sre[p1], Pi = sim[p1];
        const float Qr = sre[p2], Qi = sim[p2];
        dstA[k] = make_float2(0.5f * (Pr + Qr), 0.5f * (Pi - Qi));
        dstB[k] = make_float2(0.5f * (Pi + Qi), 0.5f * (Qr - Pr));
    }
    for (int k = 257 + t; k < CSTR; k += 256) {  // zero the 7 pad columns
        dstA[k] = make_float2(0.0f, 0.0f);
        dstB[k] = make_float2(0.0f, 0.0f);
    }
}

// ---------------------------------------------------------------------------
// Pass B: one block per (image, 8-column tile), kx in [0,263]; columns with
// kx>256 are zero pad (masked from binning). Weight 2 for kx in [1,255]
// (Hermitian partner column 512-kx maps to identical bins), weight 1 for
// kx in {0,256}. ky = rev9(storage_row).
// ---------------------------------------------------------------------------
#define LCOLS 8
#define LSTR  520

__global__ __launch_bounds__(256) void colfft_kernel(
    const float2* __restrict__ in, float* __restrict__ bins, int img_base)
{
    __shared__ float sre[LCOLS * LSTR], sim[LCOLS * LSTR];
    __shared__ float twr[256], twi[256];
    __shared__ float bsum[NBIN];
    const int t = threadIdx.x;

    {
        float s_, c_;
        sincosf(-6.283185307179586f * (float)t / 512.0f, &s_, &c_);
        twr[t] = c_; twi[t] = s_;
    }
    bsum[t] = 0.0f;

    const int li = blockIdx.y;
    const int x0 = blockIdx.x * LCOLS;
    const float2* src = in + (size_t)li * IMGC;

    #pragma unroll
    for (int it = 0; it < 16; ++it) {
        const int id = it * 256 + t;      // 0..4095
        const int y  = id >> 3;
        const int cl = id & 7;
        const float2 v = src[(size_t)y * CSTR + (x0 + cl)];
        sre[cl * LSTR + y] = v.x;
        sim[cl * LSTR + y] = v.y;
    }
    __syncthreads();

    #pragma unroll
    for (int s = 9; s >= 1; --s) {
        const int half = 1 << (s - 1);
        const int j    = t & (half - 1);
        const int i1   = ((t >> (s - 1)) << s) + j;
        const int i2   = i1 + half;
        const int tw   = j << (9 - s);
        const float wr = twr[tw], wi = twi[tw];
        #pragma unroll
        for (int c = 0; c < LCOLS; ++c) {
            float* re = sre + c * LSTR;
            float* im = sim + c * LSTR;
            const float ur = re[i1], ui = im[i1];
            const float vr = re[i2], vi = im[i2];
            const float dr = ur - vr, di = ui - vi;
            re[i1] = ur + vr;            im[i1] = ui + vi;
            re[i2] = dr * wr - di * wi;  im[i2] = dr * wi + di * wr;
        }
        __syncthreads();
    }

    #pragma unroll
    for (int it = 0; it < 16; ++it) {
        const int id = it * 256 + t;
        const int q  = id >> 3;           // storage row
        const int cl = id & 7;
        const int kx = x0 + cl;
        if (kx > 256) continue;
        const float re = sre[cl * LSTR + q];
        const float im = sim[cl * LSTR + q];
        const float val = logf(re * re + im * im + EPSV);
        const float w = (kx == 0 || kx == 256) ? 1.0f : 2.0f;
        const int ky = rev9(q);
        const int dy = ky - 256, dx = kx - 256;
        const int r2 = dy * dy + dx * dx;
        const int b  = (int)sqrtf((float)r2);
        if (b < NBIN) atomicAdd(&bsum[b], val * w);
    }
    __syncthreads();

    const int g = img_base + li;
    atomicAdd(&bins[(size_t)g * NBIN + t], bsum[t]);
}

// ---------------------------------------------------------------------------
// Bin counts over the full 512x512 grid (image-independent).
// ---------------------------------------------------------------------------
__global__ __launch_bounds__(256) void counts_kernel(float* __restrict__ cnt)
{
    __shared__ float c[NBIN];
    const int t = threadIdx.x;
    c[t] = 0.0f;
    __syncthreads();

    const int base = blockIdx.x * 4096;
    #pragma unroll
    for (int i = 0; i < 16; ++i) {
        const int id = base + i * 256 + t;
        const int y = id >> 9, x = id & 511;
        const int dy = y - 256, dx = x - 256;
        const int r2 = dy * dy + dx * dx;
        const int b  = (int)sqrtf((float)r2);
        if (b < NBIN) atomicAdd(&c[b], 1.0f);
    }
    __syncthreads();
    if (c[t] != 0.0f) atomicAdd(&cnt[t], c[t]);
}

// ---------------------------------------------------------------------------
// Finalize: mean over (pair, bin) of |sum_p - sum_t| / cnt.
// ---------------------------------------------------------------------------
__global__ __launch_bounds__(256) void finalize_kernel(
    const float* __restrict__ bins, const float* __restrict__ cnt,
    float* __restrict__ out)
{
    __shared__ float red[256];
    const int t = threadIdx.x;

    float acc = 0.0f;
    for (int id = t; id < NIMG_PER * NBIN; id += 256) {
        const int i = id >> 8;
        const int r = id & 255;
        const float d = fabsf(bins[(size_t)i * NBIN + r]
                            - bins[(size_t)(NIMG_PER + i) * NBIN + r]);
        acc += d / cnt[r];
    }
    red[t] = acc;
    __syncthreads();
    for (int w = 128; w > 0; w >>= 1) {
        if (t < w) red[t] += red[t + w];
        __syncthreads();
    }
    if (t == 0) out[0] = red[0] / (float)(NIMG_PER * NBIN);
}

// ---------------------------------------------------------------------------
extern "C" void kernel_launch(void* const* d_in, const int* in_sizes, int n_in,
                              void* d_out, int out_size, void* d_ws, size_t ws_size,
                              hipStream_t stream)
{
    const float* pred = (const float*)d_in[0];
    const float* targ = (const float*)d_in[1];
    float* out = (float*)d_out;

    char* ws = (char*)d_ws;
    float* bins = (float*)ws;                        // NIMG*NBIN accumulators
    float* cnt  = bins + (size_t)NIMG * NBIN;        // NBIN counts
    const size_t zero_bytes = ((size_t)NIMG * NBIN + NBIN) * sizeof(float);
    const size_t off = (zero_bytes + 255) & ~(size_t)255;
    float2* cbuf = (float2*)(ws + off);

    const size_t per_img = (size_t)IMGC * sizeof(float2);   // ~1.03 MiB
    size_t avail = (ws_size > off) ? (ws_size - off) : 0;
    int chunk = (int)(avail / per_img);
    if (chunk > NIMG) chunk = NIMG;
    if (chunk < 1) chunk = 1;

    hipMemsetAsync(bins, 0, zero_bytes, stream);
    counts_kernel<<<dim3(64), dim3(256), 0, stream>>>(cnt);

    for (int base = 0; base < NIMG; base += chunk) {
        const int n = (NIMG - base < chunk) ? (NIMG - base) : chunk;
        dim3 gA(HH / 2, n), gB(NTILE, n), blk(256);
        rowfft_kernel<<<gA, blk, 0, stream>>>(pred, targ, cbuf, base);
        colfft_kernel<<<gB, blk, 0, stream>>>(cbuf, bins, base);
    }

    finalize_kernel<<<dim3(1), dim3(256), 0, stream>>>(bins, cnt, out);
}

// Round 3
// 256.835 us; speedup vs baseline: 3.9332x; 1.6944x over previous
//
#include <hip/hip_runtime.h>
#include <math.h>

#define HH 512
#define WW 512
#define IMG (HH*WW)
#define NIMG_PER 96   // B*C = 32*3
#define NIMG 192      // pred + targ
#define NBIN 256      // max_r
#define EPSV 1e-8f

#define CSTR 264               // padded column count (257 used + 7 pad)
#define IMGC (512*CSTR)        // float2 elements per image in cbuf
#define NTILE 33               // ceil(257/8) column tiles
#define SLOT 580               // padded per-FFT LDS stride (floats); fsw(511)=574

// octal-digit reversal of 9-bit index (3 radix-8 stages)
__device__ __forceinline__ int drev(int s) {
    return ((s & 7) << 6) | (s & 56) | (s >> 6);
}
// bank swizzle: makes all FFT/unpack access patterns <=2-way on 32 banks
__device__ __forceinline__ int fsw(int a) { return a + (a >> 3); }

__device__ __forceinline__ float2 cmul(float2 a, float2 b) {
    return make_float2(a.x*b.x - a.y*b.y, a.x*b.y + a.y*b.x);
}
#define C_ADD(a,b) make_float2((a).x+(b).x, (a).y+(b).y)
#define C_SUB(a,b) make_float2((a).x-(b).x, (a).y-(b).y)
#define C_NI(a)    make_float2((a).y, -(a).x)   // * (-i)

// radix-8 DIF butterfly, negative exponent (w8 = e^{-i pi/4})
__device__ __forceinline__ void bfly8(float2 x[8]) {
    const float R = 0.70710678118654752440f;
    float2 t0=C_ADD(x[0],x[4]), t4=C_SUB(x[0],x[4]);
    float2 t1=C_ADD(x[1],x[5]), t5=C_SUB(x[1],x[5]);
    float2 t2=C_ADD(x[2],x[6]), t6=C_SUB(x[2],x[6]);
    float2 t3=C_ADD(x[3],x[7]), t7=C_SUB(x[3],x[7]);
    float2 u0=C_ADD(t0,t2), u2=C_SUB(t0,t2);
    float2 u1=C_ADD(t1,t3), u3=C_SUB(t1,t3);
    x[0]=C_ADD(u0,u1); x[4]=C_SUB(u0,u1);
    {
        float2 n3 = C_NI(u3);
        x[2]=C_ADD(u2,n3); x[6]=C_SUB(u2,n3);
    }
    float2 s1 = make_float2(R*(t5.x + t5.y), R*(t5.y - t5.x));   // t5 * (R - iR)
    float2 s2 = C_NI(t6);                                        // t6 * (-i)
    float2 s3 = make_float2(R*(t7.y - t7.x), -R*(t7.x + t7.y));  // t7 * (-R - iR)
    float2 v0=C_ADD(t4,s2), v2=C_SUB(t4,s2);
    float2 v1=C_ADD(s1,s3), v3=C_SUB(s1,s3);
    x[1]=C_ADD(v0,v1); x[5]=C_SUB(v0,v1);
    {
        float2 n3 = C_NI(v3);
        x[3]=C_ADD(v2,n3); x[7]=C_SUB(v2,n3);
    }
}

// apply w^(j) for j=1..7 where w = exp(-2*pi*i*base/den), via power chain
__device__ __forceinline__ void twiddle7(float2* x, float base, float den) {
    float sn, cs;
    sincosf(-6.28318530717958647692f * base / den, &sn, &cs);
    float2 w1 = make_float2(cs, sn), w = w1;
    x[1] = cmul(x[1], w);
    #pragma unroll
    for (int j = 2; j < 8; ++j) { w = cmul(w, w1); x[j] = cmul(x[j], w); }
}

// ---------------------------------------------------------------------------
// Pass A: one block per 4 row-pairs (8 image rows). Pack rows (2p,2p+1) as
// a+ib, radix-8 512-pt DIF FFT (3 stages), Hermitian unpack, write kx=0..256.
// ---------------------------------------------------------------------------
__global__ __launch_bounds__(256) void rowfft_kernel(
    const float* __restrict__ pred, const float* __restrict__ targ,
    float2* __restrict__ out, int img_base)
{
    __shared__ float LB[4640];          // sre[4*580] | sim[4*580]; reused as planes
    float* sre = LB;
    float* sim = LB + 4*SLOT;
    const int t = threadIdx.x;

    const int pb = blockIdx.x;          // 0..63 (covers rows pb*8 .. pb*8+7)
    const int li = blockIdx.y;
    const int g  = img_base + li;
    const float* img = (g < NIMG_PER) ? (pred + (size_t)g * IMG)
                                      : (targ + (size_t)(g - NIMG_PER) * IMG);
    const float4* src4 = (const float4*)(img + (size_t)(pb*8) * WW);

    #pragma unroll
    for (int it = 0; it < 4; ++it) {
        const int id = it*256 + t;      // 0..1023 = r*128 + x4
        const int r  = id >> 7;
        const int x4 = id & 127;
        const float4 v = src4[id];
        float* dst = ((r & 1) ? sim : sre) + (r >> 1) * SLOT;
        const int b = 4*x4 + (x4 >> 1); // = fsw(4*x4)
        dst[b+0]=v.x; dst[b+1]=v.y; dst[b+2]=v.z; dst[b+3]=v.w;
    }
    __syncthreads();

    const int i    = t & 63;
    const int slot = t >> 6;
    float* re = sre + slot*SLOT;
    float* im = sim + slot*SLOT;
    float2 x[8];

    // ---- stage 1: stride 64, twiddle w512^(i*j)
    #pragma unroll
    for (int j = 0; j < 8; ++j) { int a = fsw(i + 64*j); x[j] = make_float2(re[a], im[a]); }
    bfly8(x);
    twiddle7(x, (float)i, 512.0f);
    #pragma unroll
    for (int j = 0; j < 8; ++j) { int a = fsw(i + 64*j); re[a] = x[j].x; im[a] = x[j].y; }
    __syncthreads();

    // ---- stage 2: groups of 64, twiddle w64^(i2*j)
    const int grp = i >> 3, i2 = i & 7;
    #pragma unroll
    for (int j = 0; j < 8; ++j) { int a = fsw(64*grp + i2 + 8*j); x[j] = make_float2(re[a], im[a]); }
    bfly8(x);
    twiddle7(x, (float)i2, 64.0f);
    #pragma unroll
    for (int j = 0; j < 8; ++j) { int a = fsw(64*grp + i2 + 8*j); re[a] = x[j].x; im[a] = x[j].y; }
    __syncthreads();

    // ---- stage 3: contiguous 8, no twiddle
    #pragma unroll
    for (int j = 0; j < 8; ++j) { int a = fsw(8*i + j); x[j] = make_float2(re[a], im[a]); }
    bfly8(x);
    #pragma unroll
    for (int j = 0; j < 8; ++j) { int a = fsw(8*i + j); re[a] = x[j].x; im[a] = x[j].y; }
    __syncthreads();

    // ---- Hermitian unpack. Wave w in {1,2,3}: k = drev(t) covers k=w mod 8
    // (p1 = t, conflict-free). Wave 0: lanes 0..31 -> k=8d+4; 32..63 -> k=8(d-32).
    // Each Hermitian pair {k, 512-k} covered exactly once; kk = min of pair.
    const int w_ = t >> 6;
    int k;
    if (w_ > 0) k = ((t & 7) << 6) | (t & 56) | w_;   // drev(t)
    else        k = (t < 32) ? (8*t + 4) : (8*(t - 32));
    const int kk = (k <= 256) ? k : (512 - k);
    const int a1 = fsw(drev(kk));
    const int a2 = (t == 0) ? fsw(drev(256)) : fsw(drev(512 - kk));

    float2 Fa[4], Fb[4], Qs[4];
    #pragma unroll
    for (int s = 0; s < 4; ++s) {
        const float Pr = sre[s*SLOT + a1], Pi2 = sim[s*SLOT + a1];
        const float Qr = sre[s*SLOT + a2], Qi  = sim[s*SLOT + a2];
        Fa[s] = make_float2(0.5f*(Pr+Qr), 0.5f*(Pi2-Qi));
        Fb[s] = make_float2(0.5f*(Pi2+Qi), 0.5f*(Qr-Pr));
        if (t == 0) {                    // k=0 self-pair: F(0)=(Re, 0)
            Fa[s] = make_float2(Pr, 0.0f);
            Fb[s] = make_float2(Pi2, 0.0f);
        }
        Qs[s] = make_float2(Qr, Qi);     // lane 0: Z(256) -> k=256 outputs
    }
    __syncthreads();

    // planes overwrite LB: plane (4s+p), p={FaRe,FaIm,FbRe,FbIm}, width 290
    {
        const int fb = fsw(kk);
        #pragma unroll
        for (int s = 0; s < 4; ++s) {
            LB[(4*s+0)*290 + fb] = Fa[s].x;
            LB[(4*s+1)*290 + fb] = Fa[s].y;
            LB[(4*s+2)*290 + fb] = Fb[s].x;
            LB[(4*s+3)*290 + fb] = Fb[s].y;
        }
    }
    if (t == 0) {
        const int fb = fsw(256);         // F(256) = (Re Z(256), 0)
        #pragma unroll
        for (int s = 0; s < 4; ++s) {
            LB[(4*s+0)*290 + fb] = Qs[s].x;
            LB[(4*s+1)*290 + fb] = 0.0f;
            LB[(4*s+2)*290 + fb] = Qs[s].y;
            LB[(4*s+3)*290 + fb] = 0.0f;
        }
    }
    __syncthreads();

    // coalesced copy planes -> global (rows 2p=A, 2p+1=B), zero pad cols
    float2* dst = out + (size_t)li * IMGC + (size_t)(pb*8) * CSTR;
    #pragma unroll
    for (int r = 0; r < 8; ++r) {
        const int pbase = (r >> 1)*4 + (r & 1)*2;
        float2* drow = dst + (size_t)r * CSTR;
        {
            const int fc = fsw(t);
            drow[t] = make_float2(LB[pbase*290 + fc], LB[(pbase+1)*290 + fc]);
        }
        if (t < 8) {
            const int c = 256 + t;
            float2 v = make_float2(0.0f, 0.0f);
            if (c == 256) {
                const int fc = fsw(256);
                v = make_float2(LB[pbase*290 + fc], LB[(pbase+1)*290 + fc]);
            }
            drow[c] = v;
        }
    }
}

// ---------------------------------------------------------------------------
// Pass B: one block per (image, 8-column tile). 8 radix-8 column FFTs
// (2 per thread, shared twiddles), PSD+log+radial bin from registers.
// ---------------------------------------------------------------------------
__global__ __launch_bounds__(256) void colfft_kernel(
    const float2* __restrict__ in, float* __restrict__ bins, int img_base)
{
    __shared__ float sre[8*SLOT], sim[8*SLOT];
    __shared__ float bsum[NBIN];
    const int t = threadIdx.x;
    bsum[t] = 0.0f;

    const int li = blockIdx.y;
    const int x0 = blockIdx.x * 8;
    const float2* src = in + (size_t)li * IMGC;

    #pragma unroll
    for (int it = 0; it < 16; ++it) {
        const int id = it*256 + t;        // 0..4095
        const int y  = id >> 3;
        const int cl = id & 7;
        const float2 v = src[(size_t)y * CSTR + (x0 + cl)];
        const int a = cl*SLOT + fsw(y);
        sre[a] = v.x; sim[a] = v.y;
    }
    __syncthreads();

    const int i  = t & 63;
    const int c0 = t >> 6;                // slots c0 and c0+4
    float2 x[2][8];

    // ---- stage 1
    #pragma unroll
    for (int sl = 0; sl < 2; ++sl) {
        float* re = sre + (c0 + 4*sl)*SLOT;
        float* im = sim + (c0 + 4*sl)*SLOT;
        #pragma unroll
        for (int j = 0; j < 8; ++j) { int a = fsw(i + 64*j); x[sl][j] = make_float2(re[a], im[a]); }
        bfly8(x[sl]);
    }
    {
        float sn, cs; sincosf(-6.28318530717958647692f * (float)i / 512.0f, &sn, &cs);
        float2 w1 = make_float2(cs, sn), w = w1;
        x[0][1] = cmul(x[0][1], w); x[1][1] = cmul(x[1][1], w);
        #pragma unroll
        for (int j = 2; j < 8; ++j) {
            w = cmul(w, w1);
            x[0][j] = cmul(x[0][j], w); x[1][j] = cmul(x[1][j], w);
        }
    }
    #pragma unroll
    for (int sl = 0; sl < 2; ++sl) {
        float* re = sre + (c0 + 4*sl)*SLOT;
        float* im = sim + (c0 + 4*sl)*SLOT;
        #pragma unroll
        for (int j = 0; j < 8; ++j) { int a = fsw(i + 64*j); re[a] = x[sl][j].x; im[a] = x[sl][j].y; }
    }
    __syncthreads();

    // ---- stage 2
    const int grp = i >> 3, i2 = i & 7;
    #pragma unroll
    for (int sl = 0; sl < 2; ++sl) {
        float* re = sre + (c0 + 4*sl)*SLOT;
        float* im = sim + (c0 + 4*sl)*SLOT;
        #pragma unroll
        for (int j = 0; j < 8; ++j) { int a = fsw(64*grp + i2 + 8*j); x[sl][j] = make_float2(re[a], im[a]); }
        bfly8(x[sl]);
    }
    {
        float sn, cs; sincosf(-6.28318530717958647692f * (float)i2 / 64.0f, &sn, &cs);
        float2 w1 = make_float2(cs, sn), w = w1;
        x[0][1] = cmul(x[0][1], w); x[1][1] = cmul(x[1][1], w);
        #pragma unroll
        for (int j = 2; j < 8; ++j) {
            w = cmul(w, w1);
            x[0][j] = cmul(x[0][j], w); x[1][j] = cmul(x[1][j], w);
        }
    }
    #pragma unroll
    for (int sl = 0; sl < 2; ++sl) {
        float* re = sre + (c0 + 4*sl)*SLOT;
        float* im = sim + (c0 + 4*sl)*SLOT;
        #pragma unroll
        for (int j = 0; j < 8; ++j) { int a = fsw(64*grp + i2 + 8*j); re[a] = x[sl][j].x; im[a] = x[sl][j].y; }
    }
    __syncthreads();

    // ---- stage 3 + PSD + radial bin straight from registers
    #pragma unroll
    for (int sl = 0; sl < 2; ++sl) {
        const int cl = c0 + 4*sl;
        const int kx = x0 + cl;
        float* re = sre + cl*SLOT;
        float* im = sim + cl*SLOT;
        float2 y8[8];
        #pragma unroll
        for (int j = 0; j < 8; ++j) { int a = fsw(8*i + j); y8[j] = make_float2(re[a], im[a]); }
        bfly8(y8);
        if (kx <= 256) {
            const float wgt = (kx == 0 || kx == 256) ? 1.0f : 2.0f;
            const int dx = kx - 256;
            #pragma unroll
            for (int j = 0; j < 8; ++j) {
                const int q  = 8*i + j;
                const int ky = drev(q);
                const float val = __logf(y8[j].x*y8[j].x + y8[j].y*y8[j].y + EPSV);
                const int dy = ky - 256;
                const int b  = (int)sqrtf((float)(dy*dy + dx*dx));
                if (b < NBIN) atomicAdd(&bsum[b], wgt * val);
            }
        }
    }
    __syncthreads();

    atomicAdd(&bins[(size_t)(img_base + li) * NBIN + t], bsum[t]);
}

// ---------------------------------------------------------------------------
// Bin counts over the full 512x512 grid (image-independent).
// ---------------------------------------------------------------------------
__global__ __launch_bounds__(256) void counts_kernel(float* __restrict__ cnt)
{
    __shared__ float c[NBIN];
    const int t = threadIdx.x;
    c[t] = 0.0f;
    __syncthreads();

    const int base = blockIdx.x * 4096;
    #pragma unroll
    for (int i = 0; i < 16; ++i) {
        const int id = base + i * 256 + t;
        const int y = id >> 9, xx = id & 511;
        const int dy = y - 256, dx = xx - 256;
        const int b  = (int)sqrtf((float)(dy*dy + dx*dx));
        if (b < NBIN) atomicAdd(&c[b], 1.0f);
    }
    __syncthreads();
    if (c[t] != 0.0f) atomicAdd(&cnt[t], c[t]);
}

// ---------------------------------------------------------------------------
// Finalize: mean over (pair, bin) of |sum_p - sum_t| / cnt.
// ---------------------------------------------------------------------------
__global__ __launch_bounds__(256) void finalize_kernel(
    const float* __restrict__ bins, const float* __restrict__ cnt,
    float* __restrict__ out)
{
    __shared__ float red[256];
    const int t = threadIdx.x;

    float acc = 0.0f;
    for (int id = t; id < NIMG_PER * NBIN; id += 256) {
        const int i = id >> 8;
        const int r = id & 255;
        const float d = fabsf(bins[(size_t)i * NBIN + r]
                            - bins[(size_t)(NIMG_PER + i) * NBIN + r]);
        acc += d / cnt[r];
    }
    red[t] = acc;
    __syncthreads();
    for (int w = 128; w > 0; w >>= 1) {
        if (t < w) red[t] += red[t + w];
        __syncthreads();
    }
    if (t == 0) out[0] = red[0] / (float)(NIMG_PER * NBIN);
}

// ---------------------------------------------------------------------------
extern "C" void kernel_launch(void* const* d_in, const int* in_sizes, int n_in,
                              void* d_out, int out_size, void* d_ws, size_t ws_size,
                              hipStream_t stream)
{
    const float* pred = (const float*)d_in[0];
    const float* targ = (const float*)d_in[1];
    float* out = (float*)d_out;

    char* ws = (char*)d_ws;
    float* bins = (float*)ws;                        // NIMG*NBIN accumulators
    float* cnt  = bins + (size_t)NIMG * NBIN;        // NBIN counts
    const size_t zero_bytes = ((size_t)NIMG * NBIN + NBIN) * sizeof(float);
    const size_t off = (zero_bytes + 255) & ~(size_t)255;
    float2* cbuf = (float2*)(ws + off);

    const size_t per_img = (size_t)IMGC * sizeof(float2);   // ~1.03 MiB
    size_t avail = (ws_size > off) ? (ws_size - off) : 0;
    int chunk = (int)(avail / per_img);
    if (chunk > NIMG) chunk = NIMG;
    if (chunk < 1) chunk = 1;

    hipMemsetAsync(bins, 0, zero_bytes, stream);
    counts_kernel<<<dim3(64), dim3(256), 0, stream>>>(cnt);

    for (int base = 0; base < NIMG; base += chunk) {
        const int n = (NIMG - base < chunk) ? (NIMG - base) : chunk;
        dim3 gA(HH / 8, n), gB(NTILE, n), blk(256);
        rowfft_kernel<<<gA, blk, 0, stream>>>(pred, targ, cbuf, base);
        colfft_kernel<<<gB, blk, 0, stream>>>(cbuf, bins, base);
    }

    finalize_kernel<<<dim3(1), dim3(256), 0, stream>>>(bins, cnt, out);
}